// Round 5
// baseline (781.833 us; speedup 1.0000x reference)
//
#include <hip/hip_runtime.h>

// Persistent cooperative ConvLSTM2D x2. B=4 T=16 H=W=64 Cin=F=32, k=3 SAME.
// 256 blocks (1/CU) x 512 thr; block = row (b,y), both layers.
// Phase p: {L1 step p, L2 step p-2}; 17 grid barriers; weights + cell state
// register-resident for the whole kernel; h planes ping-pong in ws (bf16).

typedef __bf16 bf16x8 __attribute__((ext_vector_type(8)));
typedef float f32x4 __attribute__((ext_vector_type(4)));

#define WPK_ELEMS 73728   // 18 kchunks * 8 ntiles * 64 lanes * 8 (per layer)
#define PLANE 524288      // 4*64*64*32 bf16 elems per h plane

__device__ __forceinline__ float fsigmoid(float z) {
    return 1.0f / (1.0f + __expf(-z));
}
__device__ __forceinline__ float ftanh(float z) {
    z = fminf(15.0f, fmaxf(-15.0f, z));
    float e = __expf(2.0f * z);
    return (e - 1.0f) / (e + 1.0f);
}

// Pack wk/wr (3,3,32,128) fp32 -> wpk[layer][cix][nt][lane][j2] bf16.
// cix = tap*2 + src (src0 = input kernel, src1 = recurrent kernel).
// col n' = nt*16 + (lane&15): gate = nt&3, f = (nt>>2)*16 + (lane&15).
__global__ __launch_bounds__(256) void pack_weights(
    const float* __restrict__ wk1, const float* __restrict__ wr1,
    const float* __restrict__ wk2, const float* __restrict__ wr2,
    __bf16* __restrict__ wpk)
{
    int i = blockIdx.x * 256 + threadIdx.x;
    if (i >= 2 * WPK_ELEMS) return;
    int layer = i / WPK_ELEMS;
    int r = i - layer * WPK_ELEMS;
    int j2 = r & 7;
    int L  = (r >> 3) & 63;
    int nt = (r >> 9) & 7;
    int cix = r >> 12;            // 0..17
    int tap = cix >> 1, src = cix & 1;
    int s = ((L >> 4) << 3) + j2;            // channel 0..31
    int gate = nt & 3;
    int f = ((nt >> 2) << 4) + (L & 15);
    int n = (gate << 5) + f;
    const float* w = layer ? (src ? wr2 : wk2) : (src ? wr1 : wk1);
    wpk[i] = (__bf16)w[(tap * 32 + s) * 128 + n];
}

__global__ __launch_bounds__(512, 2) void clstm_coop(
    const float* __restrict__ x,          // (4,16,64,64,32) fp32
    const __bf16* __restrict__ wpk1,
    const __bf16* __restrict__ wpk2,
    const float* __restrict__ bias1,
    const float* __restrict__ bias2,
    __bf16* __restrict__ h1buf,           // 3 planes (4,64,64,32) bf16
    __bf16* __restrict__ h2buf,           // 2 planes
    int* __restrict__ cnt,                // 18 phase counters
    int* __restrict__ gen,                // generation word
    float* __restrict__ out)              // (4,16,64,64,32) fp32
{
    // tiles: 0 = x@p, 1 = h1@(p-1) [L1 recurrent], 2 = h1@(p-2) [L2 input],
    //        3 = h2@(p-3) [L2 recurrent]. 3 rows x 66 cols x 32ch, 36-pad.
    __shared__ __bf16 tiles[4][3 * 66 * 36];

    const int tid = threadIdx.x;
    const int blk = blockIdx.x;
    const int b = blk >> 6, y = blk & 63;

    const int w     = tid >> 6;
    const int L     = tid & 63;
    const int layer = w >> 2;
    const int fh    = (w >> 1) & 1;
    const int mh    = w & 1;
    const int c     = L & 15;
    const int q     = L >> 4;

    // ---- weights: 72 fragments register-resident for the whole kernel ----
    const bf16x8* wpkv = (const bf16x8*)(layer ? wpk2 : wpk1);
    const float*  bias = layer ? bias2 : bias1;
    bf16x8 wb[2][9][4];
    #pragma unroll
    for (int s = 0; s < 2; ++s)
        #pragma unroll
        for (int tap = 0; tap < 9; ++tap)
            #pragma unroll
            for (int g = 0; g < 4; ++g)
                wb[s][tap][g] = wpkv[(size_t)(((tap * 2 + s) * 8) + fh * 4 + g) * 64 + L];

    float bv[4];
    #pragma unroll
    for (int g = 0; g < 4; ++g) bv[g] = bias[g * 32 + fh * 16 + c];

    float creg[2][4];   // cell state, register-resident across all steps
    #pragma unroll
    for (int m2 = 0; m2 < 2; ++m2)
        #pragma unroll
        for (int r = 0; r < 4; ++r) creg[m2][r] = 0.f;

    const size_t rowbase = ((size_t)b * 64 + y) * 64 * 32;
    const int fcol = fh * 16 + c;

    for (int p = 0; p < 18; ++p) {
        // ---- stage LDS tiles (all 512 threads) ----
        for (int i = tid; i < 3168; i += 512) {
            const int tile = i / 792;
            const int r2 = i - tile * 792;
            const int g  = r2 & 3;
            const int rc = r2 >> 2;       // 0..197
            const int cc = rc % 66;
            const int dy = rc / 66;
            bool act;
            if      (tile == 0) act = (p <= 15);
            else if (tile == 1) act = (p >= 1 && p <= 15);
            else if (tile == 2) act = (p >= 2);
            else                act = (p >= 3);
            if (!act) continue;
            const int yy = y + dy - 1;
            const int xc = cc - 1;
            bf16x8 v = {};
            if (yy >= 0 && yy < 64 && xc >= 0 && xc < 64) {
                if (tile == 0) {
                    const float* src = x + (((size_t)(b * 16 + p)) * 4096 +
                                            (size_t)yy * 64 + xc) * 32 + g * 8;
                    const float4 f0 = *(const float4*)src;
                    const float4 f1 = *(const float4*)(src + 4);
                    v[0] = (__bf16)f0.x; v[1] = (__bf16)f0.y;
                    v[2] = (__bf16)f0.z; v[3] = (__bf16)f0.w;
                    v[4] = (__bf16)f1.x; v[5] = (__bf16)f1.y;
                    v[6] = (__bf16)f1.z; v[7] = (__bf16)f1.w;
                } else {
                    const __bf16* src;
                    if (tile == 1)      src = h1buf + (size_t)((p - 1) % 3) * PLANE;
                    else if (tile == 2) src = h1buf + (size_t)((p - 2) % 3) * PLANE;
                    else                src = h2buf + (size_t)((p - 3) & 1) * PLANE;
                    v = *(const bf16x8*)(src + ((size_t)(b * 64 + yy) * 64 + xc) * 32 + g * 8);
                }
            }
            *(bf16x8*)(&tiles[tile][(dy * 66 + cc) * 36 + g * 8]) = v;
        }
        __syncthreads();

        // ---- compute this wave's layer-step ----
        const bool active = layer ? (p >= 2) : (p <= 15);
        const int t = layer ? (p - 2) : p;
        if (active) {
            const __bf16* s0 = layer ? tiles[2] : tiles[0];
            const __bf16* s1 = layer ? tiles[3] : tiles[1];

            f32x4 acc[2][4];
            #pragma unroll
            for (int m2 = 0; m2 < 2; ++m2)
                #pragma unroll
                for (int g = 0; g < 4; ++g)
                    acc[m2][g] = (f32x4){bv[g], bv[g], bv[g], bv[g]};

            #pragma unroll
            for (int tap = 0; tap < 9; ++tap) {
                const int dyk = tap / 3, dxk = tap % 3;
                const int base = (dyk * 66 + mh * 32 + c + dxk) * 36 + q * 8;
                const bf16x8 a00 = *(const bf16x8*)(s0 + base);
                const bf16x8 a01 = *(const bf16x8*)(s0 + base + 16 * 36);
                acc[0][0] = __builtin_amdgcn_mfma_f32_16x16x32_bf16(a00, wb[0][tap][0], acc[0][0], 0, 0, 0);
                acc[0][1] = __builtin_amdgcn_mfma_f32_16x16x32_bf16(a00, wb[0][tap][1], acc[0][1], 0, 0, 0);
                acc[0][2] = __builtin_amdgcn_mfma_f32_16x16x32_bf16(a00, wb[0][tap][2], acc[0][2], 0, 0, 0);
                acc[0][3] = __builtin_amdgcn_mfma_f32_16x16x32_bf16(a00, wb[0][tap][3], acc[0][3], 0, 0, 0);
                acc[1][0] = __builtin_amdgcn_mfma_f32_16x16x32_bf16(a01, wb[0][tap][0], acc[1][0], 0, 0, 0);
                acc[1][1] = __builtin_amdgcn_mfma_f32_16x16x32_bf16(a01, wb[0][tap][1], acc[1][1], 0, 0, 0);
                acc[1][2] = __builtin_amdgcn_mfma_f32_16x16x32_bf16(a01, wb[0][tap][2], acc[1][2], 0, 0, 0);
                acc[1][3] = __builtin_amdgcn_mfma_f32_16x16x32_bf16(a01, wb[0][tap][3], acc[1][3], 0, 0, 0);
                if (t > 0) {
                    const bf16x8 a10 = *(const bf16x8*)(s1 + base);
                    const bf16x8 a11 = *(const bf16x8*)(s1 + base + 16 * 36);
                    acc[0][0] = __builtin_amdgcn_mfma_f32_16x16x32_bf16(a10, wb[1][tap][0], acc[0][0], 0, 0, 0);
                    acc[0][1] = __builtin_amdgcn_mfma_f32_16x16x32_bf16(a10, wb[1][tap][1], acc[0][1], 0, 0, 0);
                    acc[0][2] = __builtin_amdgcn_mfma_f32_16x16x32_bf16(a10, wb[1][tap][2], acc[0][2], 0, 0, 0);
                    acc[0][3] = __builtin_amdgcn_mfma_f32_16x16x32_bf16(a10, wb[1][tap][3], acc[0][3], 0, 0, 0);
                    acc[1][0] = __builtin_amdgcn_mfma_f32_16x16x32_bf16(a11, wb[1][tap][0], acc[1][0], 0, 0, 0);
                    acc[1][1] = __builtin_amdgcn_mfma_f32_16x16x32_bf16(a11, wb[1][tap][1], acc[1][1], 0, 0, 0);
                    acc[1][2] = __builtin_amdgcn_mfma_f32_16x16x32_bf16(a11, wb[1][tap][2], acc[1][2], 0, 0, 0);
                    acc[1][3] = __builtin_amdgcn_mfma_f32_16x16x32_bf16(a11, wb[1][tap][3], acc[1][3], 0, 0, 0);
                }
            }

            // ---- epilogue: gate, update register c, store h (+ out) ----
            __bf16* hw = (layer ? h2buf + (size_t)(p & 1) * PLANE
                                : h1buf + (size_t)(p % 3) * PLANE) + rowbase;
            float* outp = out + (((size_t)b * 16 + t) * 4096 + (size_t)y * 64) * 32;
            #pragma unroll
            for (int m2 = 0; m2 < 2; ++m2) {
                #pragma unroll
                for (int r = 0; r < 4; ++r) {
                    const float ig = fsigmoid(acc[m2][0][r]);
                    const float fg = fsigmoid(acc[m2][1][r]);
                    const float gg = ftanh(acc[m2][2][r]);
                    const float og = fsigmoid(acc[m2][3][r]);
                    const float cn = ig * gg + (t ? fg * creg[m2][r] : 0.0f);
                    creg[m2][r] = cn;
                    const float hv = og * ftanh(cn);
                    const int xw = mh * 32 + m2 * 16 + q * 4 + r;
                    hw[(size_t)xw * 32 + fcol] = (__bf16)hv;
                    if (layer) outp[(size_t)xw * 32 + fcol] = hv;
                }
            }
        }

        // ---- grid barrier (phase-indexed counter + generation word) ----
        if (p < 17) {
            __syncthreads();
            if (tid == 0) {
                int v = __hip_atomic_fetch_add(&cnt[p], 1, __ATOMIC_ACQ_REL,
                                               __HIP_MEMORY_SCOPE_AGENT);
                if (v == 255) {
                    __hip_atomic_store(gen, p + 1, __ATOMIC_RELEASE,
                                       __HIP_MEMORY_SCOPE_AGENT);
                } else {
                    int guard = 0;
                    while (__hip_atomic_load(gen, __ATOMIC_ACQUIRE,
                                             __HIP_MEMORY_SCOPE_AGENT) < p + 1) {
                        __builtin_amdgcn_s_sleep(2);
                        if (++guard > 5000000) break;   // bail, never hang
                    }
                }
            }
            __syncthreads();
        }
    }
}

extern "C" void kernel_launch(void* const* d_in, const int* in_sizes, int n_in,
                              void* d_out, int out_size, void* d_ws, size_t ws_size,
                              hipStream_t stream)
{
    const float* x   = (const float*)d_in[0];
    const float* k1  = (const float*)d_in[1];
    const float* rk1 = (const float*)d_in[2];
    const float* b1  = (const float*)d_in[3];
    const float* k2  = (const float*)d_in[4];
    const float* rk2 = (const float*)d_in[5];
    const float* b2  = (const float*)d_in[6];
    float* out = (float*)d_out;

    int* cnt = (int*)d_ws;                         // 18 counters
    int* gen = cnt + 24;
    __bf16* wpk1  = (__bf16*)((char*)d_ws + 256);
    __bf16* wpk2  = wpk1 + WPK_ELEMS;
    __bf16* h1buf = wpk2 + WPK_ELEMS;              // 3 planes
    __bf16* h2buf = h1buf + 3 * PLANE;             // 2 planes

    hipMemsetAsync(d_ws, 0, 256, stream);
    pack_weights<<<(2 * WPK_ELEMS + 255) / 256, 256, 0, stream>>>(k1, rk1, k2, rk2, wpk1);

    void* args[] = {(void*)&x, (void*)&wpk1, (void*)&wpk2, (void*)&b1, (void*)&b2,
                    (void*)&h1buf, (void*)&h2buf, (void*)&cnt, (void*)&gen, (void*)&out};
    hipLaunchCooperativeKernel((void*)clstm_coop, dim3(256), dim3(512), args, 0, stream);
}

// Round 7
// 483.438 us; speedup vs baseline: 1.6172x; 1.6172x over previous
//
#include <hip/hip_runtime.h>

// ConvLSTM2D x2, temporal-blocked multi-launch. B=4 T=16 H=W=64 Cin=F=32.
// 9 launches; launch j: L1 computes t=2j,2j+1; L2 computes t=2j-2,2j-1.
// Block owns 2 rows; step A computes 4 rows (2 redundant halo rows) so step B
// needs no cross-block sync. XCD-contiguous row mapping for L2 halo locality.
// h1: 4 planes (t%4), h2: 2 odd-parity planes (written by L2 step B),
// c: 2 odd-parity fp32 planes.

typedef __bf16 bf16x8 __attribute__((ext_vector_type(8)));
typedef float f32x4 __attribute__((ext_vector_type(4)));

#define WPK_ELEMS 73728   // per layer: 18 kchunks * 8 ntiles * 64 lanes * 8
#define PLANE 524288      // 4*64*64*32 elems per plane

__device__ __forceinline__ float fsigmoid(float z) {
    return 1.0f / (1.0f + __expf(-z));
}
__device__ __forceinline__ float ftanh(float z) {
    z = fminf(15.0f, fmaxf(-15.0f, z));
    float e = __expf(2.0f * z);
    return (e - 1.0f) / (e + 1.0f);
}

__global__ __launch_bounds__(256) void pack_weights(
    const float* __restrict__ wk1, const float* __restrict__ wr1,
    const float* __restrict__ wk2, const float* __restrict__ wr2,
    __bf16* __restrict__ wpk)
{
    int i = blockIdx.x * 256 + threadIdx.x;
    if (i >= 2 * WPK_ELEMS) return;
    int layer = i / WPK_ELEMS;
    int r = i - layer * WPK_ELEMS;
    int j2 = r & 7;
    int L  = (r >> 3) & 63;
    int nt = (r >> 9) & 7;
    int cix = r >> 12;
    int tap = cix >> 1, src = cix & 1;
    int s = ((L >> 4) << 3) + j2;
    int gate = nt & 3;
    int f = ((nt >> 2) << 4) + (L & 15);
    int n = (gate << 5) + f;
    const float* w = layer ? (src ? wr2 : wk2) : (src ? wr1 : wk1);
    wpk[i] = (__bf16)w[(tap * 32 + s) * 128 + n];
}

__device__ __forceinline__ bf16x8 cvt8(const float* p) {
    const float4 f0 = *(const float4*)p;
    const float4 f1 = *(const float4*)(p + 4);
    bf16x8 v;
    v[0] = (__bf16)f0.x; v[1] = (__bf16)f0.y;
    v[2] = (__bf16)f0.z; v[3] = (__bf16)f0.w;
    v[4] = (__bf16)f1.x; v[5] = (__bf16)f1.y;
    v[6] = (__bf16)f1.z; v[7] = (__bf16)f1.w;
    return v;
}

#define MFMA8(A0, A1, WB)                                                          \
    acc[0][0] = __builtin_amdgcn_mfma_f32_16x16x32_bf16(A0, WB[0], acc[0][0], 0, 0, 0); \
    acc[0][1] = __builtin_amdgcn_mfma_f32_16x16x32_bf16(A0, WB[1], acc[0][1], 0, 0, 0); \
    acc[0][2] = __builtin_amdgcn_mfma_f32_16x16x32_bf16(A0, WB[2], acc[0][2], 0, 0, 0); \
    acc[0][3] = __builtin_amdgcn_mfma_f32_16x16x32_bf16(A0, WB[3], acc[0][3], 0, 0, 0); \
    acc[1][0] = __builtin_amdgcn_mfma_f32_16x16x32_bf16(A1, WB[0], acc[1][0], 0, 0, 0); \
    acc[1][1] = __builtin_amdgcn_mfma_f32_16x16x32_bf16(A1, WB[1], acc[1][1], 0, 0, 0); \
    acc[1][2] = __builtin_amdgcn_mfma_f32_16x16x32_bf16(A1, WB[2], acc[1][2], 0, 0, 0); \
    acc[1][3] = __builtin_amdgcn_mfma_f32_16x16x32_bf16(A1, WB[3], acc[1][3], 0, 0, 0);

__global__ __launch_bounds__(512, 1) void clstm_pair(
    const float* __restrict__ x,
    const __bf16* __restrict__ wpk1, const __bf16* __restrict__ wpk2,
    const float* __restrict__ bias1, const float* __restrict__ bias2,
    __bf16* __restrict__ h1buf,       // 4 planes, t%4
    __bf16* __restrict__ h2buf,       // 2 planes, odd t: (t>>1)&1
    float* __restrict__ c1,           // 2 planes, odd t: (t>>1)&1
    float* __restrict__ c2,
    float* __restrict__ out, int j)
{
    __shared__ __bf16 tA0[6 * 66 * 36];   // step-A input-conv src
    __shared__ __bf16 tA1[6 * 66 * 36];   // step-A recurrent src
    __shared__ __bf16 tB0[4 * 66 * 36];   // step-B input-conv src
    __shared__ __bf16 tHA[4 * 66 * 36];   // h@T0 local (zero borders)
    __shared__ float  cpass[2 * 64 * 32]; // c@T0, own 2 rows

    const int blk = blockIdx.x;
    const int k = blk >> 3;
    const int layer = k >> 4;
    if (layer ? (j < 1) : (j > 7)) return;
    const int grp = (blk & 7) * 16 + (k & 15);   // XCD-contiguous rows
    const int T0 = layer ? (2 * j - 2) : (2 * j);
    const int R = grp << 1;
    const int b = R >> 6, y0 = R & 63;

    const int tid = threadIdx.x;
    const int w = tid >> 6, L = tid & 63;
    const int wr = w >> 1;          // A: window row; B: (row, col-half)
    const int fh = w & 1;
    const int c = L & 15, q = L >> 4;
    const int f = fh * 16 + c;

    // ---- register-resident weights: 72 fragments ----
    const bf16x8* wpkv = (const bf16x8*)(layer ? wpk2 : wpk1);
    const float* bias = layer ? bias2 : bias1;
    bf16x8 wb[2][9][4];
    #pragma unroll
    for (int s = 0; s < 2; ++s)
        #pragma unroll
        for (int tap = 0; tap < 9; ++tap)
            #pragma unroll
            for (int g = 0; g < 4; ++g)
                wb[s][tap][g] = wpkv[(size_t)(((tap * 2 + s) * 8) + fh * 4 + g) * 64 + L];

    float bv[4];
    #pragma unroll
    for (int g = 0; g < 4; ++g) bv[g] = bias[g * 32 + f];

    // ---- staging sources ----
    const float*  xA = x + (size_t)(b * 16 + T0) * 131072;
    const float*  xB = xA + 131072;
    const __bf16* hs0A = h1buf + (size_t)(T0 & 3) * PLANE;
    const __bf16* hs0B = h1buf + (size_t)((T0 + 1) & 3) * PLANE;
    const __bf16* hs1A = layer ? (h2buf + (size_t)(((T0 - 1) >> 1) & 1) * PLANE)
                               : (h1buf + (size_t)((T0 - 1) & 3) * PLANE);

    // loop 1: A tiles (6 rows each, window y0-2..y0+3)
    const int nA = T0 ? 3168 : 1584;
    for (int i = tid; i < nA; i += 512) {
        const int tile = (i >= 1584) ? 1 : 0;
        const int r2 = i - tile * 1584;
        const int g = r2 & 3;
        const int rc = r2 >> 2;
        const int cc = rc % 66;
        const int row = rc / 66;
        const int yy = y0 - 2 + row;
        const int xc = cc - 1;
        bf16x8 v = {};
        if (yy >= 0 && yy < 64 && xc >= 0 && xc < 64) {
            if (!layer && tile == 0) {
                v = cvt8(xA + (((size_t)yy * 64 + xc) * 32 + g * 8));
            } else {
                const __bf16* s = tile ? hs1A : hs0A;
                v = *(const bf16x8*)(s + (((size_t)(b * 64 + yy)) * 64 + xc) * 32 + g * 8);
            }
        }
        *(bf16x8*)((tile ? tA1 : tA0) + (row * 66 + cc) * 36 + g * 8) = v;
    }
    // loop 2: B tile (4 rows, window y0-1..y0+2)
    for (int i = tid; i < 1056; i += 512) {
        const int g = i & 3;
        const int rc = i >> 2;
        const int cc = rc % 66;
        const int row = rc / 66;
        const int yy = y0 - 1 + row;
        const int xc = cc - 1;
        bf16x8 v = {};
        if (yy >= 0 && yy < 64 && xc >= 0 && xc < 64) {
            if (!layer) v = cvt8(xB + (((size_t)yy * 64 + xc) * 32 + g * 8));
            else        v = *(const bf16x8*)(hs0B + (((size_t)(b * 64 + yy)) * 64 + xc) * 32 + g * 8);
        }
        *(bf16x8*)(tB0 + (row * 66 + cc) * 36 + g * 8) = v;
    }
    // loop 3: zero tHA (borders + invalid rows must be 0)
    for (int i = tid; i < 1188; i += 512)
        *(bf16x8*)(tHA + i * 8) = (bf16x8){};
    __syncthreads();

    // ---- step A: compute h@T0, c@T0 on 4 window rows (y0-1..y0+2) ----
    const int ra = y0 - 1 + wr;
    const bool rvalid = (ra >= 0 && ra < 64);
    const bool own = (wr == 1 || wr == 2);
    const float* crd = (layer ? c2 : c1) + (size_t)(((T0 - 1) >> 1) & 1) * PLANE;
    float* cwr = (layer ? c2 : c1) + (size_t)(((T0 + 1) >> 1) & 1) * PLANE;
    const size_t rowA = (size_t)(b * 64 + (rvalid ? ra : 0)) * 2048;

    #pragma unroll
    for (int mp = 0; mp < 2; ++mp) {
        f32x4 acc[2][4];
        #pragma unroll
        for (int m2 = 0; m2 < 2; ++m2)
            #pragma unroll
            for (int g = 0; g < 4; ++g)
                acc[m2][g] = (f32x4){bv[g], bv[g], bv[g], bv[g]};

        #pragma unroll
        for (int tap = 0; tap < 9; ++tap) {
            const int dyk = tap / 3, dxk = tap % 3;
            const int base0 = ((wr + dyk) * 66 + mp * 32 + c + dxk) * 36 + q * 8;
            const bf16x8 a0 = *(const bf16x8*)(tA0 + base0);
            const bf16x8 a1 = *(const bf16x8*)(tA0 + base0 + 576);
            MFMA8(a0, a1, wb[0][tap]);
            if (T0 > 0) {
                const bf16x8 h0 = *(const bf16x8*)(tA1 + base0);
                const bf16x8 h1v = *(const bf16x8*)(tA1 + base0 + 576);
                MFMA8(h0, h1v, wb[1][tap]);
            }
        }
        #pragma unroll
        for (int m2 = 0; m2 < 2; ++m2) {
            #pragma unroll
            for (int r = 0; r < 4; ++r) {
                const int px = mp * 32 + m2 * 16 + q * 4 + r;
                const float ig = fsigmoid(acc[m2][0][r]);
                const float fg = fsigmoid(acc[m2][1][r]);
                const float gg = ftanh(acc[m2][2][r]);
                const float og = fsigmoid(acc[m2][3][r]);
                float cold = 0.f;
                if (T0 > 0 && rvalid) cold = crd[rowA + (size_t)px * 32 + f];
                const float cn = (T0 ? fg * cold : 0.f) + ig * gg;
                const float hv = og * ftanh(cn);
                if (rvalid) tHA[(wr * 66 + px + 1) * 36 + f] = (__bf16)hv;
                if (own) {
                    cpass[(wr - 1) * 2048 + px * 32 + f] = cn;
                    if (layer)
                        out[((size_t)(b * 16 + T0) * 4096 + (size_t)ra * 64 + px) * 32 + f] = hv;
                    else
                        h1buf[(size_t)(T0 & 3) * PLANE + rowA + (size_t)px * 32 + f] = (__bf16)hv;
                }
            }
        }
    }
    __syncthreads();

    // ---- step B: compute h@T0+1, c@T0+1 on own 2 rows ----
    {
        const int o = wr >> 1;            // own row index 0..1
        const int rb = y0 + o;
        const int pxb = (wr & 1) * 32;
        f32x4 acc[2][4];
        #pragma unroll
        for (int m2 = 0; m2 < 2; ++m2)
            #pragma unroll
            for (int g = 0; g < 4; ++g)
                acc[m2][g] = (f32x4){bv[g], bv[g], bv[g], bv[g]};

        #pragma unroll
        for (int tap = 0; tap < 9; ++tap) {
            const int dyk = tap / 3, dxk = tap % 3;
            const int baseS = ((o + dyk) * 66 + pxb + c + dxk) * 36 + q * 8;
            const bf16x8 a0 = *(const bf16x8*)(tB0 + baseS);
            const bf16x8 a1 = *(const bf16x8*)(tB0 + baseS + 576);
            MFMA8(a0, a1, wb[0][tap]);
            const bf16x8 h0 = *(const bf16x8*)(tHA + baseS);
            const bf16x8 h1v = *(const bf16x8*)(tHA + baseS + 576);
            MFMA8(h0, h1v, wb[1][tap]);
        }
        const size_t rowB = (size_t)(b * 64 + rb) * 2048;
        __bf16* h2w = h2buf + (size_t)(((T0 + 1) >> 1) & 1) * PLANE;
        #pragma unroll
        for (int m2 = 0; m2 < 2; ++m2) {
            #pragma unroll
            for (int r = 0; r < 4; ++r) {
                const int px = pxb + m2 * 16 + q * 4 + r;
                const float ig = fsigmoid(acc[m2][0][r]);
                const float fg = fsigmoid(acc[m2][1][r]);
                const float gg = ftanh(acc[m2][2][r]);
                const float og = fsigmoid(acc[m2][3][r]);
                const float cold = cpass[o * 2048 + px * 32 + f];
                const float cn = fg * cold + ig * gg;
                const float hv = og * ftanh(cn);
                cwr[rowB + (size_t)px * 32 + f] = cn;
                if (layer) {
                    out[((size_t)(b * 16 + T0 + 1) * 4096 + (size_t)rb * 64 + px) * 32 + f] = hv;
                    h2w[rowB + (size_t)px * 32 + f] = (__bf16)hv;   // FIX: recurrent src for next launch
                } else {
                    h1buf[(size_t)((T0 + 1) & 3) * PLANE + rowB + (size_t)px * 32 + f] = (__bf16)hv;
                }
            }
        }
    }
}

extern "C" void kernel_launch(void* const* d_in, const int* in_sizes, int n_in,
                              void* d_out, int out_size, void* d_ws, size_t ws_size,
                              hipStream_t stream)
{
    const float* x   = (const float*)d_in[0];
    const float* k1  = (const float*)d_in[1];
    const float* rk1 = (const float*)d_in[2];
    const float* b1  = (const float*)d_in[3];
    const float* k2  = (const float*)d_in[4];
    const float* rk2 = (const float*)d_in[5];
    const float* b2  = (const float*)d_in[6];
    float* out = (float*)d_out;

    __bf16* wpk1  = (__bf16*)d_ws;
    __bf16* wpk2  = wpk1 + WPK_ELEMS;
    __bf16* h1buf = wpk2 + WPK_ELEMS;             // 4 planes bf16
    __bf16* h2buf = h1buf + 4 * (size_t)PLANE;    // 2 planes bf16
    float*  c1    = (float*)(h2buf + 2 * (size_t)PLANE);  // 2 planes fp32
    float*  c2    = c1 + 2 * (size_t)PLANE;

    pack_weights<<<(2 * WPK_ELEMS + 255) / 256, 256, 0, stream>>>(k1, rk1, k2, rk2, wpk1);

    for (int j = 0; j <= 8; ++j) {
        clstm_pair<<<256, 512, 0, stream>>>(
            x, wpk1, wpk2, b1, b2, h1buf, h2buf, c1, c2, out, j);
    }
}

// Round 8
// 417.970 us; speedup vs baseline: 1.8705x; 1.1566x over previous
//
#include <hip/hip_runtime.h>

// ConvLSTM2D x2, 2-step temporal blocking, 9 launches.
// Launch j: L1 computes t=2j,2j+1; L2 computes t=2j-2,2j-1 (prev-launch deps only).
// Block = 2 own rows, 512 thr. Step A computes 4 window rows (2 redundant halo)
// so step B needs no cross-block sync; h@A passes via LDS (tHA), c via cpass.
// NO weight arrays (B-frags streamed from L2 per tap — avoids scratch spill).
// Input-src A-fragments loaded DIRECT from global (L1-cached), zero-pad via
// pointer select to a zeroed ws region. LDS: h-recurrent tile + tHA + cpass.

typedef __bf16 bf16x8 __attribute__((ext_vector_type(8)));
typedef float f32x4 __attribute__((ext_vector_type(4)));

#define WPK_ELEMS 73728   // per layer: 18 kchunks * 8 ntiles * 64 lanes * 8
#define PLANE 524288      // 4*64*64*32 elems per plane

__device__ __forceinline__ float fsigmoid(float z) {
    return 1.0f / (1.0f + __expf(-z));
}
__device__ __forceinline__ float ftanh(float z) {
    z = fminf(15.0f, fmaxf(-15.0f, z));
    float e = __expf(2.0f * z);
    return (e - 1.0f) / (e + 1.0f);
}

__global__ __launch_bounds__(256) void pack_weights(
    const float* __restrict__ wk1, const float* __restrict__ wr1,
    const float* __restrict__ wk2, const float* __restrict__ wr2,
    __bf16* __restrict__ wpk)
{
    int i = blockIdx.x * 256 + threadIdx.x;
    if (i >= 2 * WPK_ELEMS) return;
    int layer = i / WPK_ELEMS;
    int r = i - layer * WPK_ELEMS;
    int j2 = r & 7;
    int L  = (r >> 3) & 63;
    int nt = (r >> 9) & 7;
    int cix = r >> 12;
    int tap = cix >> 1, src = cix & 1;
    int s = ((L >> 4) << 3) + j2;
    int gate = nt & 3;
    int f = ((nt >> 2) << 4) + (L & 15);
    int n = (gate << 5) + f;
    const float* w = layer ? (src ? wr2 : wk2) : (src ? wr1 : wk1);
    wpk[i] = (__bf16)w[(tap * 32 + s) * 128 + n];
}

__device__ __forceinline__ bf16x8 cvt8(const float* p) {
    const float4 f0 = *(const float4*)p;
    const float4 f1 = *(const float4*)(p + 4);
    bf16x8 v;
    v[0] = (__bf16)f0.x; v[1] = (__bf16)f0.y;
    v[2] = (__bf16)f0.z; v[3] = (__bf16)f0.w;
    v[4] = (__bf16)f1.x; v[5] = (__bf16)f1.y;
    v[6] = (__bf16)f1.z; v[7] = (__bf16)f1.w;
    return v;
}

#define MFMA8(A0, A1, WP)                                                              \
    acc[0][0] = __builtin_amdgcn_mfma_f32_16x16x32_bf16(A0, WP[0],   acc[0][0], 0, 0, 0); \
    acc[0][1] = __builtin_amdgcn_mfma_f32_16x16x32_bf16(A0, WP[64],  acc[0][1], 0, 0, 0); \
    acc[0][2] = __builtin_amdgcn_mfma_f32_16x16x32_bf16(A0, WP[128], acc[0][2], 0, 0, 0); \
    acc[0][3] = __builtin_amdgcn_mfma_f32_16x16x32_bf16(A0, WP[192], acc[0][3], 0, 0, 0); \
    acc[1][0] = __builtin_amdgcn_mfma_f32_16x16x32_bf16(A1, WP[0],   acc[1][0], 0, 0, 0); \
    acc[1][1] = __builtin_amdgcn_mfma_f32_16x16x32_bf16(A1, WP[64],  acc[1][1], 0, 0, 0); \
    acc[1][2] = __builtin_amdgcn_mfma_f32_16x16x32_bf16(A1, WP[128], acc[1][2], 0, 0, 0); \
    acc[1][3] = __builtin_amdgcn_mfma_f32_16x16x32_bf16(A1, WP[192], acc[1][3], 0, 0, 0);

__global__ __launch_bounds__(512, 2) void clstm_pair2(
    const float* __restrict__ x,
    const __bf16* __restrict__ wpk1, const __bf16* __restrict__ wpk2,
    const float* __restrict__ bias1, const float* __restrict__ bias2,
    __bf16* __restrict__ h1buf,       // 4 planes, t%4
    __bf16* __restrict__ h2buf,       // 2 planes (odd t): ((t)>>1)&1
    float* __restrict__ c1,           // 2 planes (odd t)
    float* __restrict__ c2,
    const float* __restrict__ zbuf,   // >=32B of zeros (pad source)
    float* __restrict__ out, int j)
{
    __shared__ __bf16 tA1[6 * 66 * 36];   // step-A recurrent h, rows y0-2..y0+3
    __shared__ __bf16 tHA[4 * 66 * 36];   // h@T0, rows y0-1..y0+2 (zero borders)
    __shared__ float  cpass[2 * 64 * 32]; // c@T0, own rows

    const int blk = blockIdx.x;
    const int k = blk >> 3;
    const int layer = k >> 4;
    if (layer ? (j < 1) : (j > 7)) return;
    const int grp = (blk & 7) * 16 + (k & 15);   // XCD-contiguous rows
    const int T0 = layer ? (2 * j - 2) : (2 * j);
    const int R = grp << 1;
    const int b = R >> 6, y0 = R & 63;

    const int tid = threadIdx.x;
    const int w = tid >> 6, L = tid & 63;
    const int wr = w >> 1;          // A: window row; B: (row o, col-half)
    const int fh = w & 1;
    const int c = L & 15, q = L >> 4;
    const int f = fh * 16 + c;

    const bf16x8* wpkv = (const bf16x8*)(layer ? wpk2 : wpk1);
    const float* bias = layer ? bias2 : bias1;
    float bv[4];
    #pragma unroll
    for (int g = 0; g < 4; ++g) bv[g] = bias[g * 32 + f];

    // input-conv sources (direct global):
    const float*  xA  = x + (size_t)(b * 16 + T0) * 131072;
    const float*  xB  = xA + 131072;
    const __bf16* h1A = h1buf + (size_t)(T0 & 3) * PLANE;
    const __bf16* h1B = h1buf + (size_t)((T0 + 1) & 3) * PLANE;

    // direct fragment loader: input-conv operand at (row yy, col), ch q*8..q*8+7
    auto load_in = [&](const float* fb, const __bf16* hb, int yy, int col) -> bf16x8 {
        const bool ok = ((unsigned)yy < 64u) && ((unsigned)col < 64u);
        const int yc = ok ? yy : 0, cc = ok ? col : 0;
        if (layer == 0) {
            const float* p = ok ? (fb + ((size_t)yc * 64 + cc) * 32 + q * 8) : zbuf;
            return cvt8(p);
        } else {
            const __bf16* p = ok ? (hb + (((size_t)(b * 64 + yc)) * 64 + cc) * 32 + q * 8)
                                 : (const __bf16*)zbuf;
            return *(const bf16x8*)p;
        }
    };

    // ---- stage tA1 (recurrent src for step A) + zero tHA ----
    if (T0 > 0) {
        const __bf16* hs = layer ? (h2buf + (size_t)(((T0 - 1) >> 1) & 1) * PLANE)
                                 : (h1buf + (size_t)((T0 - 1) & 3) * PLANE);
        for (int i = tid; i < 1584; i += 512) {
            const int g = i & 3;
            const int rc = i >> 2;
            const int cc = rc % 66;
            const int row = rc / 66;
            const int yy = y0 - 2 + row;
            const int xc = cc - 1;
            bf16x8 v = {};
            if (yy >= 0 && yy < 64 && xc >= 0 && xc < 64)
                v = *(const bf16x8*)(hs + (((size_t)(b * 64 + yy)) * 64 + xc) * 32 + g * 8);
            *(bf16x8*)(tA1 + (row * 66 + cc) * 36 + g * 8) = v;
        }
    }
    for (int i = tid; i < 1188; i += 512)
        *(bf16x8*)(tHA + i * 8) = (bf16x8){};
    __syncthreads();

    // ---- step A: h@T0, c@T0 on 4 window rows (y0-1..y0+2) ----
    const int ra = y0 - 1 + wr;
    const bool rvalid = (ra >= 0 && ra < 64);
    const bool own = (wr == 1 || wr == 2);
    const float* crd = (layer ? c2 : c1) + (size_t)(((T0 - 1) >> 1) & 1) * PLANE;
    float* cwr = (layer ? c2 : c1) + (size_t)(((T0 + 1) >> 1) & 1) * PLANE;
    const size_t rowA = (size_t)(b * 64 + (rvalid ? ra : 0)) * 2048;

    #pragma unroll
    for (int mp = 0; mp < 2; ++mp) {
        f32x4 acc[2][4];
        #pragma unroll
        for (int m2 = 0; m2 < 2; ++m2)
            #pragma unroll
            for (int g = 0; g < 4; ++g)
                acc[m2][g] = (f32x4){bv[g], bv[g], bv[g], bv[g]};

        #pragma unroll
        for (int tap = 0; tap < 9; ++tap) {
            const int dyk = tap / 3, dxk = tap % 3;
            const int yy = ra + dyk - 1;
            const int col0 = mp * 32 + c + dxk - 1;
            const bf16x8 i0 = load_in(xA, h1A, yy, col0);
            const bf16x8 i1 = load_in(xA, h1A, yy, col0 + 16);
            const bf16x8* wpx = wpkv + (size_t)((tap * 2) * 8 + fh * 4) * 64 + L;
            MFMA8(i0, i1, wpx);
            if (T0 > 0) {
                const int lb = ((wr + dyk) * 66 + mp * 32 + c + dxk) * 36 + q * 8;
                const bf16x8 h0 = *(const bf16x8*)(tA1 + lb);
                const bf16x8 h1v = *(const bf16x8*)(tA1 + lb + 16 * 36);
                const bf16x8* wph = wpkv + (size_t)((tap * 2 + 1) * 8 + fh * 4) * 64 + L;
                MFMA8(h0, h1v, wph);
            }
        }
        #pragma unroll
        for (int m2 = 0; m2 < 2; ++m2) {
            #pragma unroll
            for (int r = 0; r < 4; ++r) {
                const int px = mp * 32 + m2 * 16 + q * 4 + r;
                const float ig = fsigmoid(acc[m2][0][r]);
                const float fg = fsigmoid(acc[m2][1][r]);
                const float gg = ftanh(acc[m2][2][r]);
                const float og = fsigmoid(acc[m2][3][r]);
                float cold = 0.f;
                if (T0 > 0 && rvalid) cold = crd[rowA + (size_t)px * 32 + f];
                const float cn = (T0 ? fg * cold : 0.f) + ig * gg;
                const float hv = og * ftanh(cn);
                if (rvalid) tHA[(wr * 66 + px + 1) * 36 + f] = (__bf16)hv;
                if (own) {
                    cpass[(wr - 1) * 2048 + px * 32 + f] = cn;
                    if (layer)
                        out[((size_t)(b * 16 + T0) * 4096 + (size_t)ra * 64 + px) * 32 + f] = hv;
                    else
                        h1buf[(size_t)(T0 & 3) * PLANE + rowA + (size_t)px * 32 + f] = (__bf16)hv;
                }
            }
        }
    }
    __syncthreads();

    // ---- step B: h@T0+1, c@T0+1 on own 2 rows ----
    {
        const int o = wr >> 1;
        const int rb = y0 + o;
        const int pxb = (wr & 1) * 32;
        f32x4 acc[2][4];
        #pragma unroll
        for (int m2 = 0; m2 < 2; ++m2)
            #pragma unroll
            for (int g = 0; g < 4; ++g)
                acc[m2][g] = (f32x4){bv[g], bv[g], bv[g], bv[g]};

        #pragma unroll
        for (int tap = 0; tap < 9; ++tap) {
            const int dyk = tap / 3, dxk = tap % 3;
            const int yy = rb + dyk - 1;
            const int col0 = pxb + c + dxk - 1;
            const bf16x8 i0 = load_in(xB, h1B, yy, col0);
            const bf16x8 i1 = load_in(xB, h1B, yy, col0 + 16);
            const bf16x8* wpx = wpkv + (size_t)((tap * 2) * 8 + fh * 4) * 64 + L;
            MFMA8(i0, i1, wpx);
            const int lb = ((o + dyk) * 66 + pxb + c + dxk) * 36 + q * 8;
            const bf16x8 h0 = *(const bf16x8*)(tHA + lb);
            const bf16x8 h1v = *(const bf16x8*)(tHA + lb + 16 * 36);
            const bf16x8* wph = wpkv + (size_t)((tap * 2 + 1) * 8 + fh * 4) * 64 + L;
            MFMA8(h0, h1v, wph);
        }
        const size_t rowB = (size_t)(b * 64 + rb) * 2048;
        __bf16* h2w = h2buf + (size_t)(((T0 + 1) >> 1) & 1) * PLANE;
        #pragma unroll
        for (int m2 = 0; m2 < 2; ++m2) {
            #pragma unroll
            for (int r = 0; r < 4; ++r) {
                const int px = pxb + m2 * 16 + q * 4 + r;
                const float ig = fsigmoid(acc[m2][0][r]);
                const float fg = fsigmoid(acc[m2][1][r]);
                const float gg = ftanh(acc[m2][2][r]);
                const float og = fsigmoid(acc[m2][3][r]);
                const float cold = cpass[o * 2048 + px * 32 + f];
                const float cn = fg * cold + ig * gg;
                const float hv = og * ftanh(cn);
                cwr[rowB + (size_t)px * 32 + f] = cn;
                if (layer) {
                    out[((size_t)(b * 16 + T0 + 1) * 4096 + (size_t)rb * 64 + px) * 32 + f] = hv;
                    h2w[rowB + (size_t)px * 32 + f] = (__bf16)hv;
                } else {
                    h1buf[(size_t)((T0 + 1) & 3) * PLANE + rowB + (size_t)px * 32 + f] = (__bf16)hv;
                }
            }
        }
    }
}

extern "C" void kernel_launch(void* const* d_in, const int* in_sizes, int n_in,
                              void* d_out, int out_size, void* d_ws, size_t ws_size,
                              hipStream_t stream)
{
    const float* x   = (const float*)d_in[0];
    const float* k1  = (const float*)d_in[1];
    const float* rk1 = (const float*)d_in[2];
    const float* b1  = (const float*)d_in[3];
    const float* k2  = (const float*)d_in[4];
    const float* rk2 = (const float*)d_in[5];
    const float* b2  = (const float*)d_in[6];
    float* out = (float*)d_out;

    float*  zbuf  = (float*)d_ws;                 // 256 B zeros (pad source)
    __bf16* wpk1  = (__bf16*)((char*)d_ws + 256);
    __bf16* wpk2  = wpk1 + WPK_ELEMS;
    __bf16* h1buf = wpk2 + WPK_ELEMS;             // 4 planes bf16
    __bf16* h2buf = h1buf + 4 * (size_t)PLANE;    // 2 planes bf16
    float*  c1    = (float*)(h2buf + 2 * (size_t)PLANE);  // 2 planes fp32
    float*  c2    = c1 + 2 * (size_t)PLANE;

    hipMemsetAsync(zbuf, 0, 256, stream);
    pack_weights<<<(2 * WPK_ELEMS + 255) / 256, 256, 0, stream>>>(k1, rk1, k2, rk2, wpk1);

    for (int j = 0; j <= 8; ++j) {
        clstm_pair2<<<256, 512, 0, stream>>>(
            x, wpk1, wpk2, b1, b2, h1buf, h2buf, c1, c2, zbuf, out, j);
    }
}

// Round 9
// 260.856 us; speedup vs baseline: 2.9972x; 1.6023x over previous
//
#include <hip/hip_runtime.h>

// ConvLSTM2D x2, 2-step temporal blocking, 9 launches, 1024-thr blocks.
// Launch j: L1 computes t=2j,2j+1; L2 computes t=2j-2,2j-1 (prev-launch deps).
// Block = 2 own rows; step A computes 4 window rows (2 redundant halo) so
// step B needs no cross-block sync; h@A via LDS tHA, c@A via LDS cpass.
// 16 waves: A = (wrow x fhalf x mhalf); B = (orow x fhalf x pxquarter).
// Weights streamed from L2 per tap (NO register arrays -> no scratch spill).

typedef __bf16 bf16x8 __attribute__((ext_vector_type(8)));
typedef float f32x4 __attribute__((ext_vector_type(4)));

#define WPK_ELEMS 73728   // per layer: 18 kchunks * 8 ntiles * 64 lanes * 8
#define PLANE 524288      // 4*64*64*32 elems per plane

__device__ __forceinline__ float fsigmoid(float z) {
    return 1.0f / (1.0f + __expf(-z));
}
__device__ __forceinline__ float ftanh(float z) {
    z = fminf(15.0f, fmaxf(-15.0f, z));
    float e = __expf(2.0f * z);
    return (e - 1.0f) / (e + 1.0f);
}

__global__ __launch_bounds__(256) void pack_weights(
    const float* __restrict__ wk1, const float* __restrict__ wr1,
    const float* __restrict__ wk2, const float* __restrict__ wr2,
    __bf16* __restrict__ wpk)
{
    int i = blockIdx.x * 256 + threadIdx.x;
    if (i >= 2 * WPK_ELEMS) return;
    int layer = i / WPK_ELEMS;
    int r = i - layer * WPK_ELEMS;
    int j2 = r & 7;
    int L  = (r >> 3) & 63;
    int nt = (r >> 9) & 7;
    int cix = r >> 12;
    int tap = cix >> 1, src = cix & 1;
    int s = ((L >> 4) << 3) + j2;
    int gate = nt & 3;
    int f = ((nt >> 2) << 4) + (L & 15);
    int n = (gate << 5) + f;
    const float* w = layer ? (src ? wr2 : wk2) : (src ? wr1 : wk1);
    wpk[i] = (__bf16)w[(tap * 32 + s) * 128 + n];
}

__device__ __forceinline__ bf16x8 cvt8(const float* p) {
    const float4 f0 = *(const float4*)p;
    const float4 f1 = *(const float4*)(p + 4);
    bf16x8 v;
    v[0] = (__bf16)f0.x; v[1] = (__bf16)f0.y;
    v[2] = (__bf16)f0.z; v[3] = (__bf16)f0.w;
    v[4] = (__bf16)f1.x; v[5] = (__bf16)f1.y;
    v[6] = (__bf16)f1.z; v[7] = (__bf16)f1.w;
    return v;
}

#define MFMA8(A0, A1, WP)                                                              \
    acc[0][0] = __builtin_amdgcn_mfma_f32_16x16x32_bf16(A0, WP[0],   acc[0][0], 0, 0, 0); \
    acc[0][1] = __builtin_amdgcn_mfma_f32_16x16x32_bf16(A0, WP[64],  acc[0][1], 0, 0, 0); \
    acc[0][2] = __builtin_amdgcn_mfma_f32_16x16x32_bf16(A0, WP[128], acc[0][2], 0, 0, 0); \
    acc[0][3] = __builtin_amdgcn_mfma_f32_16x16x32_bf16(A0, WP[192], acc[0][3], 0, 0, 0); \
    acc[1][0] = __builtin_amdgcn_mfma_f32_16x16x32_bf16(A1, WP[0],   acc[1][0], 0, 0, 0); \
    acc[1][1] = __builtin_amdgcn_mfma_f32_16x16x32_bf16(A1, WP[64],  acc[1][1], 0, 0, 0); \
    acc[1][2] = __builtin_amdgcn_mfma_f32_16x16x32_bf16(A1, WP[128], acc[1][2], 0, 0, 0); \
    acc[1][3] = __builtin_amdgcn_mfma_f32_16x16x32_bf16(A1, WP[192], acc[1][3], 0, 0, 0);

#define MFMA4(A0, WP)                                                                  \
    acc1[0] = __builtin_amdgcn_mfma_f32_16x16x32_bf16(A0, WP[0],   acc1[0], 0, 0, 0);     \
    acc1[1] = __builtin_amdgcn_mfma_f32_16x16x32_bf16(A0, WP[64],  acc1[1], 0, 0, 0);     \
    acc1[2] = __builtin_amdgcn_mfma_f32_16x16x32_bf16(A0, WP[128], acc1[2], 0, 0, 0);     \
    acc1[3] = __builtin_amdgcn_mfma_f32_16x16x32_bf16(A0, WP[192], acc1[3], 0, 0, 0);

__global__ __launch_bounds__(1024, 4) void clstm_pair3(
    const float* __restrict__ x,
    const __bf16* __restrict__ wpk1, const __bf16* __restrict__ wpk2,
    const float* __restrict__ bias1, const float* __restrict__ bias2,
    __bf16* __restrict__ h1buf,       // 4 planes, t%4
    __bf16* __restrict__ h2buf,       // 2 planes (odd t): (t>>1)&1
    float* __restrict__ c1,           // 2 planes (odd t)
    float* __restrict__ c2,
    float* __restrict__ out, int j)
{
    __shared__ __bf16 tXA[6 * 66 * 36];   // step-A input src (x@T0 or h1@T0)
    __shared__ __bf16 tRA[6 * 66 * 36];   // step-A recurrent src (h@T0-1)
    __shared__ __bf16 tXB[4 * 66 * 36];   // step-B input src (x@T0+1 or h1@T0+1)
    __shared__ __bf16 tHA[4 * 66 * 36];   // h@T0 local (zero borders)
    __shared__ float  cpass[2 * 64 * 32]; // c@T0 own rows

    const int blk = blockIdx.x;
    const int k = blk >> 3;
    const int layer = k >> 4;
    if (layer ? (j < 1) : (j > 7)) return;
    const int grp = (blk & 7) * 16 + (k & 15);   // XCD-contiguous rows
    const int T0 = layer ? (2 * j - 2) : (2 * j);
    const int R = grp << 1;
    const int b = R >> 6, y0 = R & 63;

    const int tid = threadIdx.x;
    const int wid = tid >> 6, L = tid & 63;
    const int c = L & 15, q = L >> 4;

    // step-A wave decomposition: (window row, f-half, m-half)
    const int wr  = wid >> 2;
    const int fhA = (wid >> 1) & 1;
    const int mpA = wid & 1;
    const int fA  = fhA * 16 + c;
    // step-B wave decomposition: (own row, f-half, px-quarter)
    const int o   = wid >> 3;
    const int fhB = (wid >> 2) & 1;
    const int pxq = wid & 3;
    const int fB  = fhB * 16 + c;

    const bf16x8* wpkv = (const bf16x8*)(layer ? wpk2 : wpk1);
    const float* bias = layer ? bias2 : bias1;
    float bvA[4], bvB[4];
    #pragma unroll
    for (int g = 0; g < 4; ++g) {
        bvA[g] = bias[g * 32 + fA];
        bvB[g] = bias[g * 32 + fB];
    }

    // ---- staging sources ----
    const float*  xA  = x + (size_t)(b * 16 + T0) * 131072;
    const float*  xB  = xA + 131072;
    const __bf16* h1A = h1buf + (size_t)(T0 & 3) * PLANE;
    const __bf16* h1B = h1buf + (size_t)((T0 + 1) & 3) * PLANE;
    const __bf16* hRA = layer ? (h2buf + (size_t)(((T0 - 1) >> 1) & 1) * PLANE)
                              : (h1buf + (size_t)((T0 - 1) & 3) * PLANE);

    // stage tXA (+ tRA if T0>0): rows y0-2..y0+3
    const int n1 = T0 ? 3168 : 1584;
    for (int i = tid; i < n1; i += 1024) {
        const int tile = (i >= 1584);
        const int r2 = i - tile * 1584;
        const int g = r2 & 3;
        const int rc = r2 >> 2;
        const int cc = rc % 66;
        const int row = rc / 66;
        const int yy = y0 - 2 + row;
        const int xc = cc - 1;
        bf16x8 v = {};
        if (yy >= 0 && yy < 64 && xc >= 0 && xc < 64) {
            if (!layer && !tile) {
                v = cvt8(xA + ((size_t)yy * 64 + xc) * 32 + g * 8);
            } else {
                const __bf16* s = tile ? hRA : h1A;
                v = *(const bf16x8*)(s + (((size_t)(b * 64 + yy)) * 64 + xc) * 32 + g * 8);
            }
        }
        *(bf16x8*)((tile ? tRA : tXA) + (row * 66 + cc) * 36 + g * 8) = v;
    }
    // stage tXB: rows y0-1..y0+2
    for (int i = tid; i < 1056; i += 1024) {
        const int g = i & 3;
        const int rc = i >> 2;
        const int cc = rc % 66;
        const int row = rc / 66;
        const int yy = y0 - 1 + row;
        const int xc = cc - 1;
        bf16x8 v = {};
        if (yy >= 0 && yy < 64 && xc >= 0 && xc < 64) {
            if (!layer) v = cvt8(xB + ((size_t)yy * 64 + xc) * 32 + g * 8);
            else        v = *(const bf16x8*)(h1B + (((size_t)(b * 64 + yy)) * 64 + xc) * 32 + g * 8);
        }
        *(bf16x8*)(tXB + (row * 66 + cc) * 36 + g * 8) = v;
    }
    // zero tHA
    for (int i = tid; i < 1188; i += 1024)
        *(bf16x8*)(tHA + i * 8) = (bf16x8){};
    __syncthreads();

    // ---- step A: h@T0, c@T0 on 4 window rows (y0-1..y0+2), this wave: one
    //      (row, f-half, 32-px half) tile ----
    {
        const int ra = y0 - 1 + wr;
        const bool rvalid = (ra >= 0 && ra < 64);
        const bool own = (wr == 1 || wr == 2);
        const float* crd = (layer ? c2 : c1) + (size_t)(((T0 - 1) >> 1) & 1) * PLANE;
        const size_t rowA = (size_t)(b * 64 + (rvalid ? ra : 0)) * 2048;

        f32x4 acc[2][4];
        #pragma unroll
        for (int m2 = 0; m2 < 2; ++m2)
            #pragma unroll
            for (int g = 0; g < 4; ++g)
                acc[m2][g] = (f32x4){bvA[g], bvA[g], bvA[g], bvA[g]};

        #pragma unroll
        for (int tap = 0; tap < 9; ++tap) {
            const int dyk = tap / 3, dxk = tap % 3;
            const int lb = ((wr + dyk) * 66 + mpA * 32 + c + dxk) * 36 + q * 8;
            const bf16x8 a0 = *(const bf16x8*)(tXA + lb);
            const bf16x8 a1 = *(const bf16x8*)(tXA + lb + 16 * 36);
            const bf16x8* wpx = wpkv + (size_t)((tap * 2) * 8 + fhA * 4) * 64 + L;
            MFMA8(a0, a1, wpx);
            if (T0 > 0) {
                const bf16x8 h0 = *(const bf16x8*)(tRA + lb);
                const bf16x8 h1v = *(const bf16x8*)(tRA + lb + 16 * 36);
                const bf16x8* wph = wpkv + (size_t)((tap * 2 + 1) * 8 + fhA * 4) * 64 + L;
                MFMA8(h0, h1v, wph);
            }
        }
        #pragma unroll
        for (int m2 = 0; m2 < 2; ++m2) {
            #pragma unroll
            for (int r = 0; r < 4; ++r) {
                const int px = mpA * 32 + m2 * 16 + q * 4 + r;
                const float ig = fsigmoid(acc[m2][0][r]);
                const float fg = fsigmoid(acc[m2][1][r]);
                const float gg = ftanh(acc[m2][2][r]);
                const float og = fsigmoid(acc[m2][3][r]);
                float cold = 0.f;
                if (T0 > 0 && rvalid) cold = crd[rowA + (size_t)px * 32 + fA];
                const float cn = (T0 ? fg * cold : 0.f) + ig * gg;
                const float hv = og * ftanh(cn);
                if (rvalid) tHA[(wr * 66 + px + 1) * 36 + fA] = (__bf16)hv;
                if (own) {
                    cpass[(wr - 1) * 2048 + px * 32 + fA] = cn;
                    if (layer)
                        out[((size_t)(b * 16 + T0) * 4096 + (size_t)ra * 64 + px) * 32 + fA] = hv;
                    else
                        h1buf[(size_t)(T0 & 3) * PLANE + rowA + (size_t)px * 32 + fA] = (__bf16)hv;
                }
            }
        }
    }
    __syncthreads();

    // ---- step B: h@T0+1, c@T0+1 on own 2 rows; this wave: one
    //      (own row, f-half, 16-px quarter) tile ----
    {
        const int rb = y0 + o;
        float* cwr = (layer ? c2 : c1) + (size_t)(((T0 + 1) >> 1) & 1) * PLANE;

        f32x4 acc1[4];
        #pragma unroll
        for (int g = 0; g < 4; ++g)
            acc1[g] = (f32x4){bvB[g], bvB[g], bvB[g], bvB[g]};

        #pragma unroll
        for (int tap = 0; tap < 9; ++tap) {
            const int dyk = tap / 3, dxk = tap % 3;
            const int lb = ((o + dyk) * 66 + pxq * 16 + c + dxk) * 36 + q * 8;
            const bf16x8 a0 = *(const bf16x8*)(tXB + lb);
            const bf16x8* wpx = wpkv + (size_t)((tap * 2) * 8 + fhB * 4) * 64 + L;
            MFMA4(a0, wpx);
            const bf16x8 h0 = *(const bf16x8*)(tHA + lb);
            const bf16x8* wph = wpkv + (size_t)((tap * 2 + 1) * 8 + fhB * 4) * 64 + L;
            MFMA4(h0, wph);
        }
        const size_t rowB = (size_t)(b * 64 + rb) * 2048;
        __bf16* h2w = h2buf + (size_t)(((T0 + 1) >> 1) & 1) * PLANE;
        #pragma unroll
        for (int r = 0; r < 4; ++r) {
            const int px = pxq * 16 + q * 4 + r;
            const float ig = fsigmoid(acc1[0][r]);
            const float fg = fsigmoid(acc1[1][r]);
            const float gg = ftanh(acc1[2][r]);
            const float og = fsigmoid(acc1[3][r]);
            const float cold = cpass[o * 2048 + px * 32 + fB];
            const float cn = fg * cold + ig * gg;
            const float hv = og * ftanh(cn);
            cwr[rowB + (size_t)px * 32 + fB] = cn;
            if (layer) {
                out[((size_t)(b * 16 + T0 + 1) * 4096 + (size_t)rb * 64 + px) * 32 + fB] = hv;
                h2w[rowB + (size_t)px * 32 + fB] = (__bf16)hv;
            } else {
                h1buf[(size_t)((T0 + 1) & 3) * PLANE + rowB + (size_t)px * 32 + fB] = (__bf16)hv;
            }
        }
    }
}

extern "C" void kernel_launch(void* const* d_in, const int* in_sizes, int n_in,
                              void* d_out, int out_size, void* d_ws, size_t ws_size,
                              hipStream_t stream)
{
    const float* x   = (const float*)d_in[0];
    const float* k1  = (const float*)d_in[1];
    const float* rk1 = (const float*)d_in[2];
    const float* b1  = (const float*)d_in[3];
    const float* k2  = (const float*)d_in[4];
    const float* rk2 = (const float*)d_in[5];
    const float* b2  = (const float*)d_in[6];
    float* out = (float*)d_out;

    __bf16* wpk1  = (__bf16*)d_ws;
    __bf16* wpk2  = wpk1 + WPK_ELEMS;
    __bf16* h1buf = wpk2 + WPK_ELEMS;             // 4 planes bf16
    __bf16* h2buf = h1buf + 4 * (size_t)PLANE;    // 2 planes bf16
    float*  c1    = (float*)(h2buf + 2 * (size_t)PLANE);  // 2 planes fp32
    float*  c2    = c1 + 2 * (size_t)PLANE;

    pack_weights<<<(2 * WPK_ELEMS + 255) / 256, 256, 0, stream>>>(k1, rk1, k2, rk2, wpk1);

    for (int j = 0; j <= 8; ++j) {
        clstm_pair3<<<256, 1024, 0, stream>>>(
            x, wpk1, wpk2, b1, b2, h1buf, h2buf, c1, c2, out, j);
    }
}